// Round 11
// baseline (106.732 us; speedup 1.0000x reference)
//
#include <hip/hip_runtime.h>

#define Kc 512
#define Dc 64
#define Hc 64
#define Bc 16
#define Tc 16384
#define Nt (Bc * Tc)              // 262144 tokens
#define LN_EPS 1e-5f
// loss = (1 + 0.25) * mean over N*D elements
#define LOSS_SCALE (1.25f / 16777216.0f)   // 1.25 / (Nt*Dc)

#define QG_BLOCKS 256             // 1 block per CU (136 KB LDS -> 1 block/CU)
#define QG_THREADS 1024           // 16 waves
#define QG_ITERS 16               // 256*1024*16 = 4,194,304 float4s = Nt*16
#define N_PARTIALS (QG_BLOCKS * 16)   // per-wave partials = 4096

// ---------------------------------------------------------------------------
// Kernel 1: per-t-value table precompute (R7 coalesced version — WIN, keep).
// ---------------------------------------------------------------------------
__global__ __launch_bounds__(256) void precompute_kernel(
    const float* __restrict__ W1, const float* __restrict__ b1,
    const float* __restrict__ ln_g, const float* __restrict__ ln_b,
    const float* __restrict__ W2, const float* __restrict__ b2,
    const float* __restrict__ cb,
    float* __restrict__ q_table, float* __restrict__ idxf_table,
    float* __restrict__ d2_table)
{
    const int v   = blockIdx.x;      // t value, 0..511
    const int tid = threadIdx.x;     // 0..255
    const int lane = tid & 63;
    const int wave = tid >> 6;       // 0..3

    __shared__ float s_h[Hc];
    __shared__ __align__(16) float s_z[Dc];
    __shared__ float s_bd[4];
    __shared__ int   s_bk[4];
    __shared__ int   s_win;
    __shared__ float s_wd;

    // ---- encoder on the first wave only (lane = H index = D index) ----
    if (tid < 64) {
        const float norm_t = (float)v * (2.0f / (float)(Kc - 1)) - 1.0f;
        float h = norm_t * W1[lane] + b1[lane];

        float s = h;
        #pragma unroll
        for (int o = 32; o > 0; o >>= 1) s += __shfl_xor(s, o);
        const float mu = s * (1.0f / (float)Hc);
        const float d = h - mu;
        float vs = d * d;
        #pragma unroll
        for (int o = 32; o > 0; o >>= 1) vs += __shfl_xor(vs, o);
        const float var = vs * (1.0f / (float)Hc);
        float hn = d * rsqrtf(var + LN_EPS) * ln_g[lane] + ln_b[lane];
        hn = fmaxf(hn, 0.0f);
        s_h[lane] = hn;
        __builtin_amdgcn_s_waitcnt(0);   // LDS write visible within wave
        float z = b2[lane];
        #pragma unroll
        for (int hh = 0; hh < Hc; ++hh) z = fmaf(s_h[hh], W2[hh * Dc + lane], z);
        s_z[lane] = z;
    }
    __syncthreads();

    // ---- coalesced argmin: wave reads 64 consecutive float4s/iter ----
    const float4* cb4 = (const float4*)cb;
    const float4 zz = ((const float4*)s_z)[lane & 15];   // loop-invariant
    const int rowgrp = lane >> 4;                        // 0..3

    float best_d = 3.4e38f;
    int best_k = 0;
    const int base = wave * 2048;
    #pragma unroll 4
    for (int i = 0; i < 32; ++i) {
        const float4 e = cb4[base + i * 64 + lane];
        float d0 = zz.x - e.x, d1 = zz.y - e.y, d2 = zz.z - e.z, d3 = zz.w - e.w;
        float pd = d0 * d0;
        pd = fmaf(d1, d1, pd); pd = fmaf(d2, d2, pd); pd = fmaf(d3, d3, pd);
        pd += __shfl_xor(pd, 1);
        pd += __shfl_xor(pd, 2);
        pd += __shfl_xor(pd, 4);
        pd += __shfl_xor(pd, 8);
        const int k = wave * 128 + i * 4 + rowgrp;
        if (pd < best_d) { best_d = pd; best_k = k; }  // k ascends per lane
    }
    #pragma unroll
    for (int o = 32; o > 0; o >>= 1) {
        const float od = __shfl_xor(best_d, o);
        const int   ok = __shfl_xor(best_k, o);
        if (od < best_d || (od == best_d && ok < best_k)) { best_d = od; best_k = ok; }
    }
    if (lane == 0) { s_bd[wave] = best_d; s_bk[wave] = best_k; }
    __syncthreads();
    if (tid == 0) {
        float bd = s_bd[0]; int bk = s_bk[0];
        #pragma unroll
        for (int w = 1; w < 4; ++w) {
            const float od = s_bd[w]; const int ok = s_bk[w];
            if (od < bd || (od == bd && ok < bk)) { bd = od; bk = ok; }
        }
        s_win = bk; s_wd = bd;
    }
    __syncthreads();

    if (tid < 64) q_table[v * Dc + tid] = cb[s_win * Dc + tid];
    if (tid == 0) { idxf_table[v] = (float)s_win; d2_table[v] = s_wd; }
}

// ---------------------------------------------------------------------------
// Kernel 2: fully-LDS-staged gather. 256 blocks x 1024 thr, 136 KB LDS.
// R10 flaw fixed: R10 left idxf/d2 as GLOBAL loads inside the hot loop (a
// ~300cy dependency per iteration per wave) + a divergent branch. Now ALL
// tables live in LDS; hot loop is pure ds_read_b128 -> global_store with no
// branches; idx/loss handled in a branch-free coalesced epilogue (thread tid
// <-> token tokbase+tid, exactly the staged t slice).
// ---------------------------------------------------------------------------
__global__ __launch_bounds__(QG_THREADS) void qgather_kernel(
    const int* __restrict__ t, const float* __restrict__ q_table,
    const float* __restrict__ idxf_table, const float* __restrict__ d2_table,
    float* __restrict__ out_q, float* __restrict__ out_idx,
    float* __restrict__ partials)
{
    __shared__ __align__(16) float s_q[Kc * Dc];   // 128 KB
    __shared__ int   s_t[QG_THREADS];              // 4 KB
    __shared__ float s_idxf[Kc];                   // 2 KB
    __shared__ float s_d2[Kc];                     // 2 KB
    const int tid = threadIdx.x;

    // stage q_table: 8 coalesced float4 rounds x 1024 threads
    float4* s_q4 = (float4*)s_q;
    const float4* q4 = (const float4*)q_table;
    #pragma unroll
    for (int i = 0; i < (Kc * Dc / 4) / QG_THREADS; ++i)
        s_q4[i * QG_THREADS + tid] = q4[i * QG_THREADS + tid];
    // stage t slice + small tables
    const int tokbase = blockIdx.x * QG_THREADS;
    s_t[tid] = t[tokbase + tid];
    if (tid < Kc) {
        s_idxf[tid] = idxf_table[tid];
        s_d2[tid]   = d2_table[tid];
    }
    __syncthreads();

    // hot loop: pure LDS-read -> global-store, no branches, no global loads
    const int f4base = tokbase * 16;
    const int part = tid & 15;           // invariant across iters (1024%16==0)
    #pragma unroll
    for (int i = 0; i < QG_ITERS; ++i) {
        const int o = i * QG_THREADS + tid;      // 0..16383 within block
        const int tv = s_t[o >> 4];              // LDS broadcast per 16 lanes
        ((float4*)out_q)[f4base + o] = s_q4[(tv << 4) + part];
    }

    // epilogue: one token per thread, fully coalesced, LDS-only lookups
    const int tv = s_t[tid];
    out_idx[tokbase + tid] = s_idxf[tv];
    float lsum = s_d2[tv];

    // per-wave partial (no extra barrier)
    #pragma unroll
    for (int o = 32; o > 0; o >>= 1) lsum += __shfl_xor(lsum, o);
    if ((tid & 63) == 0)
        partials[blockIdx.x * (QG_THREADS / 64) + (tid >> 6)] = lsum;
}

// ---------------------------------------------------------------------------
// Kernel 3: reduce 4096 per-wave partials -> loss. Single block.
// ---------------------------------------------------------------------------
__global__ __launch_bounds__(256) void loss_reduce_kernel(
    const float* __restrict__ partials, float* __restrict__ out_loss)
{
    const int tid = threadIdx.x;
    float s = 0.0f;
    #pragma unroll
    for (int i = 0; i < N_PARTIALS / 256; ++i)
        s += partials[i * 256 + tid];
    #pragma unroll
    for (int o = 32; o > 0; o >>= 1) s += __shfl_xor(s, o);
    __shared__ float s_partial[4];
    if ((tid & 63) == 0) s_partial[tid >> 6] = s;
    __syncthreads();
    if (tid == 0)
        out_loss[0] = (s_partial[0] + s_partial[1] + s_partial[2] + s_partial[3])
                      * LOSS_SCALE;
}

extern "C" void kernel_launch(void* const* d_in, const int* in_sizes, int n_in,
                              void* d_out, int out_size, void* d_ws, size_t ws_size,
                              hipStream_t stream) {
    const int*   t        = (const int*)d_in[0];     // [B,T,1] int32
    const float* W1       = (const float*)d_in[1];   // [1,H]
    const float* b1       = (const float*)d_in[2];   // [H]
    const float* ln_g     = (const float*)d_in[3];   // [H]
    const float* ln_b     = (const float*)d_in[4];   // [H]
    const float* W2       = (const float*)d_in[5];   // [H,D]
    const float* b2       = (const float*)d_in[6];   // [D]
    const float* codebook = (const float*)d_in[7];   // [K,D]

    float* out      = (float*)d_out;
    float* out_q    = out;                     // Nt*Dc floats
    float* out_idx  = out + (size_t)Nt * Dc;   // Nt floats (idx as float)
    float* out_loss = out_idx + Nt;            // 1 float

    float* ws        = (float*)d_ws;
    float* q_table   = ws;                        // 512*64
    float* idxf_tab  = ws + Kc * Dc;              // 512
    float* d2_tab    = idxf_tab + Kc;             // 512
    float* partials  = d2_tab + Kc;               // 4096

    precompute_kernel<<<Kc, 256, 0, stream>>>(
        W1, b1, ln_g, ln_b, W2, b2, codebook,
        q_table, idxf_tab, d2_tab);

    qgather_kernel<<<QG_BLOCKS, QG_THREADS, 0, stream>>>(
        t, q_table, idxf_tab, d2_tab, out_q, out_idx, partials);

    loss_reduce_kernel<<<1, 256, 0, stream>>>(partials, out_loss);
}

// Round 12
// 104.541 us; speedup vs baseline: 1.0210x; 1.0210x over previous
//
#include <hip/hip_runtime.h>

#define Kc 512
#define Dc 64
#define Hc 64
#define Bc 16
#define Tc 16384
#define Nt (Bc * Tc)              // 262144 tokens
#define LN_EPS 1e-5f
// loss = (1 + 0.25) * mean over N*D elements
#define LOSS_SCALE (1.25f / 16777216.0f)   // 1.25 / (Nt*Dc)

#define GATHER_BLOCKS 4096
#define GATHER_THREADS 256
#define GATHER_ITERS 4            // 4096*256*4 = 4,194,304 float4s = Nt*16

// ---------------------------------------------------------------------------
// BEST-MEASURED CONFIG (R7: 104.3 us). R8 NT stores, R9 16k blocks, R10/R11
// LDS staging all neutral (104-108 band) — dependent-gather store rate is
// empirically ~2 TB/s regardless of structure; harness re-poison fills
// (~57 us) dominate the rest. Reverting to the measured minimum.
// ---------------------------------------------------------------------------

// ---------------------------------------------------------------------------
// Kernel 1: per-t-value table precompute (coalesced argmin — R7 WIN).
// 512 blocks x 256 threads. Block v: encoder (first wave) -> z[64] ->
// coalesced 4-wave argmin (wave reads 64 consecutive float4s = 4 whole rows
// per iter; 16-lane-group shfl reduce).
// ---------------------------------------------------------------------------
__global__ __launch_bounds__(256) void precompute_kernel(
    const float* __restrict__ W1, const float* __restrict__ b1,
    const float* __restrict__ ln_g, const float* __restrict__ ln_b,
    const float* __restrict__ W2, const float* __restrict__ b2,
    const float* __restrict__ cb,
    float* __restrict__ q_table, float* __restrict__ idxf_table,
    float* __restrict__ d2_table)
{
    const int v   = blockIdx.x;      // t value, 0..511
    const int tid = threadIdx.x;     // 0..255
    const int lane = tid & 63;
    const int wave = tid >> 6;       // 0..3

    __shared__ float s_h[Hc];
    __shared__ __align__(16) float s_z[Dc];
    __shared__ float s_bd[4];
    __shared__ int   s_bk[4];
    __shared__ int   s_win;
    __shared__ float s_wd;

    // ---- encoder on the first wave only (lane = H index = D index) ----
    if (tid < 64) {
        const float norm_t = (float)v * (2.0f / (float)(Kc - 1)) - 1.0f;
        float h = norm_t * W1[lane] + b1[lane];

        float s = h;
        #pragma unroll
        for (int o = 32; o > 0; o >>= 1) s += __shfl_xor(s, o);
        const float mu = s * (1.0f / (float)Hc);
        const float d = h - mu;
        float vs = d * d;
        #pragma unroll
        for (int o = 32; o > 0; o >>= 1) vs += __shfl_xor(vs, o);
        const float var = vs * (1.0f / (float)Hc);
        float hn = d * rsqrtf(var + LN_EPS) * ln_g[lane] + ln_b[lane];
        hn = fmaxf(hn, 0.0f);
        s_h[lane] = hn;
        __builtin_amdgcn_s_waitcnt(0);   // LDS write visible within wave
        // z[lane] = sum_h s_h[h] * W2[h][lane] + b2[lane]
        float z = b2[lane];
        #pragma unroll
        for (int hh = 0; hh < Hc; ++hh) z = fmaf(s_h[hh], W2[hh * Dc + lane], z);
        s_z[lane] = z;
    }
    __syncthreads();

    // ---- coalesced argmin ----
    const float4* cb4 = (const float4*)cb;
    const float4 zz = ((const float4*)s_z)[lane & 15];   // loop-invariant
    const int rowgrp = lane >> 4;                        // 0..3

    float best_d = 3.4e38f;
    int best_k = 0;
    const int base = wave * 2048;
    #pragma unroll 4
    for (int i = 0; i < 32; ++i) {
        const float4 e = cb4[base + i * 64 + lane];
        float d0 = zz.x - e.x, d1 = zz.y - e.y, d2 = zz.z - e.z, d3 = zz.w - e.w;
        float pd = d0 * d0;
        pd = fmaf(d1, d1, pd); pd = fmaf(d2, d2, pd); pd = fmaf(d3, d3, pd);
        pd += __shfl_xor(pd, 1);
        pd += __shfl_xor(pd, 2);
        pd += __shfl_xor(pd, 4);
        pd += __shfl_xor(pd, 8);
        const int k = wave * 128 + i * 4 + rowgrp;
        if (pd < best_d) { best_d = pd; best_k = k; }  // k ascends per lane
    }
    #pragma unroll
    for (int o = 32; o > 0; o >>= 1) {
        const float od = __shfl_xor(best_d, o);
        const int   ok = __shfl_xor(best_k, o);
        if (od < best_d || (od == best_d && ok < best_k)) { best_d = od; best_k = ok; }
    }
    if (lane == 0) { s_bd[wave] = best_d; s_bk[wave] = best_k; }
    __syncthreads();
    if (tid == 0) {
        float bd = s_bd[0]; int bk = s_bk[0];
        #pragma unroll
        for (int w = 1; w < 4; ++w) {
            const float od = s_bd[w]; const int ok = s_bk[w];
            if (od < bd || (od == bd && ok < bk)) { bd = od; bk = ok; }
        }
        s_win = bk; s_wd = bd;
    }
    __syncthreads();

    if (tid < 64) q_table[v * Dc + tid] = cb[s_win * Dc + tid];
    if (tid == 0) { idxf_table[v] = (float)s_win; d2_table[v] = s_wd; }
}

// ---------------------------------------------------------------------------
// Kernel 2: gather. 4096 blocks x 256, batched ILP (phase-separated loads),
// plain float4 stores, plain per-block partial store (R5: per-block
// agent-scope release/acquire = L2-flush storm, 40->180us).
// ---------------------------------------------------------------------------
__global__ __launch_bounds__(GATHER_THREADS) void gather_kernel(
    const int* __restrict__ t, const float* __restrict__ q_table,
    const float* __restrict__ idxf_table, const float* __restrict__ d2_table,
    float* __restrict__ out_q, float* __restrict__ out_idx,
    float* __restrict__ partials)
{
    const int tid = threadIdx.x;
    const int g0  = blockIdx.x * GATHER_THREADS + tid;
    const int stride = GATHER_BLOCKS * GATHER_THREADS;   // 2^20, %16==0
    const int part  = g0 & 15;                           // same for all iters

    // phase 1: all t loads in flight
    int tvs[GATHER_ITERS];
    #pragma unroll
    for (int i = 0; i < GATHER_ITERS; ++i)
        tvs[i] = t[(g0 + i * stride) >> 4];

    // phase 2: all table reads in flight (L2-resident, 128KB table)
    float4 qs[GATHER_ITERS];
    #pragma unroll
    for (int i = 0; i < GATHER_ITERS; ++i)
        qs[i] = ((const float4*)q_table)[(tvs[i] << 4) + part];

    // phase 3: streaming stores
    #pragma unroll
    for (int i = 0; i < GATHER_ITERS; ++i)
        ((float4*)out_q)[g0 + i * stride] = qs[i];

    // idx + loss contributions (part==0 lanes only; 4 lanes/wave)
    float lsum = 0.0f;
    if (part == 0) {
        #pragma unroll
        for (int i = 0; i < GATHER_ITERS; ++i) {
            const int token = (g0 + i * stride) >> 4;
            out_idx[token] = idxf_table[tvs[i]];
            lsum += d2_table[tvs[i]];
        }
    }

    // block reduction -> one partial per block (kernel boundary provides
    // cross-XCD visibility for the reduce kernel)
    #pragma unroll
    for (int o = 32; o > 0; o >>= 1) lsum += __shfl_xor(lsum, o);
    __shared__ float s_partial[4];
    if ((tid & 63) == 0) s_partial[tid >> 6] = lsum;
    __syncthreads();
    if (tid == 0)
        partials[blockIdx.x] =
            s_partial[0] + s_partial[1] + s_partial[2] + s_partial[3];
}

// ---------------------------------------------------------------------------
// Kernel 3: reduce 4096 partials -> loss. Single block, deterministic.
// ---------------------------------------------------------------------------
__global__ __launch_bounds__(256) void loss_reduce_kernel(
    const float* __restrict__ partials, float* __restrict__ out_loss)
{
    const int tid = threadIdx.x;
    float s = 0.0f;
    #pragma unroll
    for (int i = 0; i < GATHER_BLOCKS / 256; ++i)
        s += partials[i * 256 + tid];
    #pragma unroll
    for (int o = 32; o > 0; o >>= 1) s += __shfl_xor(s, o);
    __shared__ float s_partial[4];
    if ((tid & 63) == 0) s_partial[tid >> 6] = s;
    __syncthreads();
    if (tid == 0)
        out_loss[0] = (s_partial[0] + s_partial[1] + s_partial[2] + s_partial[3])
                      * LOSS_SCALE;
}

extern "C" void kernel_launch(void* const* d_in, const int* in_sizes, int n_in,
                              void* d_out, int out_size, void* d_ws, size_t ws_size,
                              hipStream_t stream) {
    const int*   t        = (const int*)d_in[0];     // [B,T,1] int32
    const float* W1       = (const float*)d_in[1];   // [1,H]
    const float* b1       = (const float*)d_in[2];   // [H]
    const float* ln_g     = (const float*)d_in[3];   // [H]
    const float* ln_b     = (const float*)d_in[4];   // [H]
    const float* W2       = (const float*)d_in[5];   // [H,D]
    const float* b2       = (const float*)d_in[6];   // [D]
    const float* codebook = (const float*)d_in[7];   // [K,D]

    float* out      = (float*)d_out;
    float* out_q    = out;                     // Nt*Dc floats
    float* out_idx  = out + (size_t)Nt * Dc;   // Nt floats (idx as float)
    float* out_loss = out_idx + Nt;            // 1 float

    float* ws        = (float*)d_ws;
    float* q_table   = ws;                        // 512*64
    float* idxf_tab  = ws + Kc * Dc;              // 512
    float* d2_tab    = idxf_tab + Kc;             // 512
    float* partials  = d2_tab + Kc;               // 4096

    precompute_kernel<<<Kc, 256, 0, stream>>>(
        W1, b1, ln_g, ln_b, W2, b2, codebook,
        q_table, idxf_tab, d2_tab);

    gather_kernel<<<GATHER_BLOCKS, GATHER_THREADS, 0, stream>>>(
        t, q_table, idxf_tab, d2_tab, out_q, out_idx, partials);

    loss_reduce_kernel<<<1, 256, 0, stream>>>(partials, out_loss);
}